// Round 1
// 1147.336 us; speedup vs baseline: 1.1948x; 1.1948x over previous
//
#include <hip/hip_runtime.h>
#include <cstddef>

// ============================================================================
// AlexCapsNet CIFAR-100 forward. Round 7: routing b-update rewritten as MFMA.
// Key trick: K=16 (capsule dim d) GEMM mapped onto 16x16x32 bf16 MFMA by
// packing the bf16x2 hi/lo split INTO the K dimension:
//   A slots k<16 = Wh[d], k>=16 = Wl[d];  B1 = (vh, vh), B2 = (vl, 0)
//   => acc = sum_d Wh*vh + Wl*vh + Wh*vl   (same 3-term split as s-pass)
// e-reduction vs u done in epilogue: 4 FMA + shfl_xor(16). blogt memset
// dropped (r=0 stores instead of accumulates). Everything else unchanged.
// ============================================================================

typedef __attribute__((ext_vector_type(8))) short bf8_t;   // 8 bf16 (4 VGPR)
typedef __attribute__((ext_vector_type(4))) float f4_t;    // 4 fp32 acc

// pack 8 fp32 -> 4 dwords of bf16-hi pairs + 4 dwords of bf16-lo pairs
__device__ inline void cvt_hilo8(const float* f, unsigned* h, unsigned* l)
{
  #pragma unroll
  for (int j = 0; j < 4; ++j) {
    unsigned u0 = __float_as_uint(f[2 * j]);
    unsigned u1 = __float_as_uint(f[2 * j + 1]);
    h[j] = (u0 >> 16) | (u1 & 0xFFFF0000u);
    float r0 = f[2 * j]     - __uint_as_float(u0 & 0xFFFF0000u);
    float r1 = f[2 * j + 1] - __uint_as_float(u1 & 0xFFFF0000u);
    l[j] = (__float_as_uint(r0) >> 16) | (__float_as_uint(r1) & 0xFFFF0000u);
  }
}

// ---------- conv1: direct 3->96 k3 s1 p1 + relu ----------
__global__ __launch_bounds__(256) void conv1_k(
    const float* __restrict__ x, const float* __restrict__ wt,
    const float* __restrict__ bias, float* __restrict__ out)
{
  int idx = blockIdx.x * 256 + threadIdx.x;
  int w = idx & 31, h = (idx >> 5) & 31;
  int t2 = idx >> 10;
  int co = t2 % 96, b = t2 / 96;
  float acc = bias[co];
  #pragma unroll
  for (int ci = 0; ci < 3; ++ci) {
    const float* xp = x + ((size_t)(b * 3 + ci) << 10);
    const float* wp = wt + (size_t)(co * 3 + ci) * 9;
    #pragma unroll
    for (int dh = 0; dh < 3; ++dh) {
      int ih = h + dh - 1;
      if (ih < 0 || ih > 31) continue;
      #pragma unroll
      for (int dw = 0; dw < 3; ++dw) {
        int iw = w + dw - 1;
        if (iw < 0 || iw > 31) continue;
        acc += xp[(ih << 5) + iw] * wp[dh * 3 + dw];
      }
    }
  }
  out[idx] = fmaxf(acc, 0.f);
}

// ---------- maxpool k3 s2 p1 ----------
__global__ __launch_bounds__(256) void maxpool_k(
    const float* __restrict__ in, float* __restrict__ out, int H)
{
  int Ho = H >> 1;
  int idx = blockIdx.x * 256 + threadIdx.x;
  int wo = idx % Ho;
  int t2 = idx / Ho;
  int ho = t2 % Ho;
  int bc = t2 / Ho;
  const float* ip = in + (size_t)bc * H * H;
  float m = -3.4e38f;
  #pragma unroll
  for (int dh = 0; dh < 3; ++dh) {
    int ih = 2 * ho - 1 + dh;
    if (ih < 0 || ih >= H) continue;
    #pragma unroll
    for (int dw = 0; dw < 3; ++dw) {
      int iw = 2 * wo - 1 + dw;
      if (iw < 0 || iw >= H) continue;
      m = fmaxf(m, ip[ih * H + iw]);
    }
  }
  out[idx] = m;
}

// ---------- conv as bf16x2-split MFMA GEMM with on-the-fly im2col ----------
template <int CI, int H, int PAD, int WO, bool SPLIT>
__global__ __launch_bounds__(256) void convgemm_mfma(
    const float* __restrict__ in, const float* __restrict__ wt,
    const float* __restrict__ bias, float* __restrict__ out,
    int CO, int relu, int KC)
{
  constexpr int K = CI * 9;
  constexpr int NPIX = WO * WO;
  __shared__ uint4 Ah[256], Al[256], Bh[256], Bl[256];
  int n0 = blockIdx.x * 64, m0 = blockIdx.y * 64;
  int kbeg = SPLIT ? blockIdx.z * KC : 0;
  int kend = SPLIT ? kbeg + KC : K;
  int t = threadIdx.x;
  int lane = t & 63;
  int wave = __builtin_amdgcn_readfirstlane(t >> 6);
  int wm = wave & 1, wn = wave >> 1;
  int lr = lane & 15, lq = lane >> 4;
  int smA = t >> 2, sgA = t & 3;

  int nn = n0 + lane;
  int bb = nn / NPIX, xy = nn - bb * NPIX;
  int ho = xy / WO, wo = xy - ho * WO;
  int ih0 = ho - PAD, iw0 = wo - PAD;
  const float* inb = in + (size_t)bb * CI * H * H;

  float fa[8], fb[8];
  auto loadA = [&](int k0) {
    const float4* ap = (const float4*)(wt + (size_t)(m0 + smA) * K + k0 + sgA * 8);
    float4 a0 = ap[0], a1 = ap[1];
    fa[0] = a0.x; fa[1] = a0.y; fa[2] = a0.z; fa[3] = a0.w;
    fa[4] = a1.x; fa[5] = a1.y; fa[6] = a1.z; fa[7] = a1.w;
  };
  auto loadB = [&](int k0) {
    int kb = k0 + wave * 8;
    int ci = kb / 9, rr = kb - ci * 9;
    int dh = rr / 3, dw = rr - dh * 3;
    #pragma unroll
    for (int j = 0; j < 8; ++j) {
      int ih = ih0 + dh, iw = iw0 + dw;
      bool ok = (ih >= 0 && ih < H && iw >= 0 && iw < H);
      fb[j] = ok ? inb[(ci * H + ih) * H + iw] : 0.f;
      if (++dw == 3) { dw = 0; if (++dh == 3) { dh = 0; ++ci; } }
    }
  };

  loadA(kbeg); loadB(kbeg);
  f4_t acc[2][2];
  #pragma unroll
  for (int mt = 0; mt < 2; ++mt)
    #pragma unroll
    for (int nt = 0; nt < 2; ++nt) acc[mt][nt] = (f4_t)0.0f;

  for (int k0 = kbeg; k0 < kend; k0 += 32) {
    if (k0 > kbeg) __syncthreads();
    unsigned ha[4], la[4], hb[4], lb[4];
    cvt_hilo8(fa, ha, la);
    cvt_hilo8(fb, hb, lb);
    Ah[sgA * 64 + smA] = make_uint4(ha[0], ha[1], ha[2], ha[3]);
    Al[sgA * 64 + smA] = make_uint4(la[0], la[1], la[2], la[3]);
    Bh[wave * 64 + lane] = make_uint4(hb[0], hb[1], hb[2], hb[3]);
    Bl[wave * 64 + lane] = make_uint4(lb[0], lb[1], lb[2], lb[3]);
    __syncthreads();
    if (k0 + 32 < kend) { loadA(k0 + 32); loadB(k0 + 32); }
    bf8_t av_h[2], av_l[2], bv_h[2], bv_l[2];
    #pragma unroll
    for (int mt = 0; mt < 2; ++mt) {
      int ui = lq * 64 + wm * 32 + mt * 16 + lr;
      av_h[mt] = *(const bf8_t*)&Ah[ui];
      av_l[mt] = *(const bf8_t*)&Al[ui];
    }
    #pragma unroll
    for (int nt = 0; nt < 2; ++nt) {
      int ui = lq * 64 + wn * 32 + nt * 16 + lr;
      bv_h[nt] = *(const bf8_t*)&Bh[ui];
      bv_l[nt] = *(const bf8_t*)&Bl[ui];
    }
    #pragma unroll
    for (int mt = 0; mt < 2; ++mt)
      #pragma unroll
      for (int nt = 0; nt < 2; ++nt) {
        acc[mt][nt] = __builtin_amdgcn_mfma_f32_16x16x32_bf16(av_h[mt], bv_h[nt], acc[mt][nt], 0, 0, 0);
        acc[mt][nt] = __builtin_amdgcn_mfma_f32_16x16x32_bf16(av_h[mt], bv_l[nt], acc[mt][nt], 0, 0, 0);
        acc[mt][nt] = __builtin_amdgcn_mfma_f32_16x16x32_bf16(av_l[mt], bv_h[nt], acc[mt][nt], 0, 0, 0);
      }
  }
  #pragma unroll
  for (int mt = 0; mt < 2; ++mt)
    #pragma unroll
    for (int nt = 0; nt < 2; ++nt) {
      #pragma unroll
      for (int r = 0; r < 4; ++r) {
        int m = m0 + wm * 32 + mt * 16 + lq * 4 + r;
        int n = n0 + wn * 32 + nt * 16 + lr;
        int b = n / NPIX, pxy = n - b * NPIX;
        size_t oidx = ((size_t)b * CO + m) * NPIX + pxy;
        if (SPLIT) {
          atomicAdd(out + oidx, acc[mt][nt][r]);
        } else {
          float vv = acc[mt][nt][r] + bias[m];
          if (relu) vv = fmaxf(vv, 0.f);
          out[oidx] = vv;
        }
      }
    }
}

// ---------- FC as bf16x2-split MFMA GEMM, split-K, atomic partials ----------
__global__ __launch_bounds__(256) void fc_mfma(
    const float* __restrict__ A, const float* __restrict__ W,
    float* __restrict__ C, int K, int N, int KC)
{
  __shared__ uint4 Ah[256], Al[256], Bh[256], Bl[256];
  int n0 = blockIdx.x * 64, m0 = blockIdx.y * 64;
  int kbeg = blockIdx.z * KC, kend = kbeg + KC;
  int t = threadIdx.x;
  int lane = t & 63;
  int wave = __builtin_amdgcn_readfirstlane(t >> 6);
  int wm = wave & 1, wn = wave >> 1;
  int lr = lane & 15, lq = lane >> 4;
  int smA = t >> 2, sgA = t & 3;

  float fa[8], fb[8];
  auto loadA = [&](int k0) {
    const float4* ap = (const float4*)(A + (size_t)(m0 + smA) * K + k0 + sgA * 8);
    float4 a0 = ap[0], a1 = ap[1];
    fa[0] = a0.x; fa[1] = a0.y; fa[2] = a0.z; fa[3] = a0.w;
    fa[4] = a1.x; fa[5] = a1.y; fa[6] = a1.z; fa[7] = a1.w;
  };
  auto loadB = [&](int k0) {
    const float* wp = W + (size_t)(k0 + wave * 8) * N + n0 + lane;
    #pragma unroll
    for (int j = 0; j < 8; ++j) fb[j] = wp[(size_t)j * N];
  };

  loadA(kbeg); loadB(kbeg);
  f4_t acc[2][2];
  #pragma unroll
  for (int mt = 0; mt < 2; ++mt)
    #pragma unroll
    for (int nt = 0; nt < 2; ++nt) acc[mt][nt] = (f4_t)0.0f;

  for (int k0 = kbeg; k0 < kend; k0 += 32) {
    if (k0 > kbeg) __syncthreads();
    unsigned ha[4], la[4], hb[4], lb[4];
    cvt_hilo8(fa, ha, la);
    cvt_hilo8(fb, hb, lb);
    Ah[sgA * 64 + smA] = make_uint4(ha[0], ha[1], ha[2], ha[3]);
    Al[sgA * 64 + smA] = make_uint4(la[0], la[1], la[2], la[3]);
    Bh[wave * 64 + lane] = make_uint4(hb[0], hb[1], hb[2], hb[3]);
    Bl[wave * 64 + lane] = make_uint4(lb[0], lb[1], lb[2], lb[3]);
    __syncthreads();
    if (k0 + 32 < kend) { loadA(k0 + 32); loadB(k0 + 32); }
    bf8_t av_h[2], av_l[2], bv_h[2], bv_l[2];
    #pragma unroll
    for (int mt = 0; mt < 2; ++mt) {
      int ui = lq * 64 + wm * 32 + mt * 16 + lr;
      av_h[mt] = *(const bf8_t*)&Ah[ui];
      av_l[mt] = *(const bf8_t*)&Al[ui];
    }
    #pragma unroll
    for (int nt = 0; nt < 2; ++nt) {
      int ui = lq * 64 + wn * 32 + nt * 16 + lr;
      bv_h[nt] = *(const bf8_t*)&Bh[ui];
      bv_l[nt] = *(const bf8_t*)&Bl[ui];
    }
    #pragma unroll
    for (int mt = 0; mt < 2; ++mt)
      #pragma unroll
      for (int nt = 0; nt < 2; ++nt) {
        acc[mt][nt] = __builtin_amdgcn_mfma_f32_16x16x32_bf16(av_h[mt], bv_h[nt], acc[mt][nt], 0, 0, 0);
        acc[mt][nt] = __builtin_amdgcn_mfma_f32_16x16x32_bf16(av_h[mt], bv_l[nt], acc[mt][nt], 0, 0, 0);
        acc[mt][nt] = __builtin_amdgcn_mfma_f32_16x16x32_bf16(av_l[mt], bv_h[nt], acc[mt][nt], 0, 0, 0);
      }
  }
  #pragma unroll
  for (int mt = 0; mt < 2; ++mt)
    #pragma unroll
    for (int nt = 0; nt < 2; ++nt) {
      #pragma unroll
      for (int r = 0; r < 4; ++r) {
        int m = m0 + wm * 32 + mt * 16 + lq * 4 + r;
        int n = n0 + wn * 32 + nt * 16 + lr;
        atomicAdd(C + (size_t)m * N + n, acc[mt][nt][r]);
      }
    }
}

// ---------- squash8 + pcaps bias; p[b,256,36] partials -> u_t[i,e,b] ----------
__global__ __launch_bounds__(256) void squash8_k(
    const float* __restrict__ p, const float* __restrict__ pb,
    float* __restrict__ ut)
{
  int idx = blockIdx.x * 256 + threadIdx.x;
  if (idx >= 147456) return;
  int b = idx & 127, i = idx >> 7;
  const float4* pp = (const float4*)(p + ((size_t)b * 1152 + i) * 8);
  float4 a = pp[0], bb = pp[1];
  float pv[8] = {a.x, a.y, a.z, a.w, bb.x, bb.y, bb.z, bb.w};
  int f0 = i * 8;
  #pragma unroll
  for (int e = 0; e < 8; ++e) pv[e] += pb[(f0 + e) / 36];
  float n2 = 0.f;
  #pragma unroll
  for (int e = 0; e < 8; ++e) n2 += pv[e] * pv[e];
  float sc = (n2 / (1.f + n2)) * rsqrtf(n2 + 1e-8f);
  #pragma unroll
  for (int e = 0; e < 8; ++e)
    ut[(size_t)i * 1024 + e * 128 + b] = pv[e] * sc;
}

// ---------- squash16: s[b,o,16] -> v[b,o,16] + v_t[o,d,b] ----------
__global__ __launch_bounds__(256) void caps_squash16(
    const float* __restrict__ s, float* __restrict__ v, float* __restrict__ vt)
{
  int idx = blockIdx.x * 256 + threadIdx.x;
  if (idx >= 12800) return;
  int b = idx / 100, o = idx % 100;
  const float4* sp = (const float4*)(s + (size_t)idx * 16);
  float4 a = sp[0], bb = sp[1], c = sp[2], d = sp[3];
  float n2 = a.x * a.x + a.y * a.y + a.z * a.z + a.w * a.w +
             bb.x * bb.x + bb.y * bb.y + bb.z * bb.z + bb.w * bb.w +
             c.x * c.x + c.y * c.y + c.z * c.z + c.w * c.w +
             d.x * d.x + d.y * d.y + d.z * d.z + d.w * d.w;
  float sc = (n2 / (1.f + n2)) * rsqrtf(n2 + 1e-8f);
  float vv[16] = {a.x, a.y, a.z, a.w, bb.x, bb.y, bb.z, bb.w,
                  c.x, c.y, c.z, c.w, d.x, d.y, d.z, d.w};
  float4* vp = (float4*)(v + (size_t)idx * 16);
  float4 o0 = {vv[0] * sc, vv[1] * sc, vv[2] * sc, vv[3] * sc};
  float4 o1 = {vv[4] * sc, vv[5] * sc, vv[6] * sc, vv[7] * sc};
  float4 o2 = {vv[8] * sc, vv[9] * sc, vv[10] * sc, vv[11] * sc};
  float4 o3 = {vv[12] * sc, vv[13] * sc, vv[14] * sc, vv[15] * sc};
  vp[0] = o0; vp[1] = o1; vp[2] = o2; vp[3] = o3;
  #pragma unroll
  for (int dd = 0; dd < 16; ++dd)
    vt[((size_t)o * 16 + dd) * 128 + b] = vv[dd] * sc;
}

// ---------- routing s-pass as per-o MFMA GEMM ----------
__global__ __launch_bounds__(256) void caps_spass_mfma(
    const float* __restrict__ W, const float* __restrict__ ut,
    const float* __restrict__ ct, float* __restrict__ s, int uniform)
{
  __shared__ uint4 Ah[512], Al[512];               // [quad(4)][b(128)] 8KB each
  int o = blockIdx.x, ks = blockIdx.y;
  int t = threadIdx.x;
  int lane = t & 63;
  int wave = __builtin_amdgcn_readfirstlane(t >> 6);
  int lr = lane & 15, lq = lane >> 4;
  int b = t & 127, half = t >> 7;                  // staging role
  int i0 = ks * 144;

  float fu[16], fc[2], fw[8];
  auto loadUC = [&](int j) {
    int ib = i0 + j * 4 + half * 2;
    #pragma unroll
    for (int q = 0; q < 2; ++q) {
      int i = ib + q;
      #pragma unroll
      for (int e = 0; e < 8; ++e)
        fu[q * 8 + e] = ut[(size_t)i * 1024 + e * 128 + b];   // coalesced
      fc[q] = uniform ? 0.01f : ct[((size_t)o * 1152 + i) * 128 + b];
    }
  };
  auto loadW = [&](int j) {
    int i = i0 + j * 4 + lq;
    const float4* wp = (const float4*)(W + (((size_t)o * 1152 + i) * 16 + lr) * 8);
    float4 w0 = wp[0], w1 = wp[1];
    fw[0] = w0.x; fw[1] = w0.y; fw[2] = w0.z; fw[3] = w0.w;
    fw[4] = w1.x; fw[5] = w1.y; fw[6] = w1.z; fw[7] = w1.w;
  };

  loadUC(0); loadW(0);
  f4_t acc[2];
  acc[0] = (f4_t)0.0f; acc[1] = (f4_t)0.0f;

  for (int j = 0; j < 36; ++j) {
    float cu[16];
    #pragma unroll
    for (int q = 0; q < 2; ++q)
      #pragma unroll
      for (int e = 0; e < 8; ++e)
        cu[q * 8 + e] = fc[q] * fu[q * 8 + e];
    unsigned h0[4], l0[4], h1[4], l1[4], wh[4], wl[4];
    cvt_hilo8(cu, h0, l0);
    cvt_hilo8(cu + 8, h1, l1);
    cvt_hilo8(fw, wh, wl);                          // current W split (before prefetch)
    uint4 uwh = make_uint4(wh[0], wh[1], wh[2], wh[3]);
    uint4 uwl = make_uint4(wl[0], wl[1], wl[2], wl[3]);
    bf8_t bfh = *(const bf8_t*)&uwh;
    bf8_t bfl = *(const bf8_t*)&uwl;
    if (j > 0) __syncthreads();
    Ah[(half * 2 + 0) * 128 + b] = make_uint4(h0[0], h0[1], h0[2], h0[3]);
    Al[(half * 2 + 0) * 128 + b] = make_uint4(l0[0], l0[1], l0[2], l0[3]);
    Ah[(half * 2 + 1) * 128 + b] = make_uint4(h1[0], h1[1], h1[2], h1[3]);
    Al[(half * 2 + 1) * 128 + b] = make_uint4(l1[0], l1[1], l1[2], l1[3]);
    __syncthreads();
    if (j + 1 < 36) { loadUC(j + 1); loadW(j + 1); }
    #pragma unroll
    for (int mt = 0; mt < 2; ++mt) {
      int bidx = wave * 16 + mt * 64 + lr;
      bf8_t avh = *(const bf8_t*)&Ah[lq * 128 + bidx];
      bf8_t avl = *(const bf8_t*)&Al[lq * 128 + bidx];
      acc[mt] = __builtin_amdgcn_mfma_f32_16x16x32_bf16(avh, bfh, acc[mt], 0, 0, 0);
      acc[mt] = __builtin_amdgcn_mfma_f32_16x16x32_bf16(avh, bfl, acc[mt], 0, 0, 0);
      acc[mt] = __builtin_amdgcn_mfma_f32_16x16x32_bf16(avl, bfh, acc[mt], 0, 0, 0);
    }
  }
  // D layout: col(d)=lane&15, row(b)=lq*4+r
  #pragma unroll
  for (int mt = 0; mt < 2; ++mt)
    #pragma unroll
    for (int r = 0; r < 4; ++r) {
      int bb = wave * 16 + mt * 64 + lq * 4 + r;
      atomicAdd(s + ((size_t)bb * 100 + o) * 16 + lr, acc[mt][r]);
    }
}

// ---------- routing b-update as MFMA (round 7) ----------
// blog[o,i,b] (+)= sum_e u[b,i,e] * T[i,e,b],  T = sum_d W[o,i,d,e] v[b,o,d]
// T via 16x16x32 bf16 MFMA with hi/lo split packed into K:
//   A[k<16]=Wh[d=k], A[k>=16]=Wl[d=k-16];  B1=(vh,vh), B2=(vl,0)
// M-tile rows = (li,e) pairs (2 li x 8 e); N = b. Epilogue: per-lane 4-FMA
// dot with u + shfl_xor(16) to combine complementary e-halves.
__global__ __launch_bounds__(256) void caps_bupdate(
    const float* __restrict__ W, const float* __restrict__ ut,
    const float* __restrict__ vt, float* __restrict__ blogt, int accum)
{
  __shared__ __align__(16) float Wt[64 * 160];   // [li][e(stride 20)][d] 40KB
  int o = blockIdx.x, ic = blockIdx.y;
  int t = threadIdx.x;
  int lane = t & 63;
  int wave = __builtin_amdgcn_readfirstlane(t >> 6);
  int lr = lane & 15, lq = lane >> 4;
  int dhalf = (lq & 1) << 3;        // which 8 d's this lq-quarter covers
  int hl = lq >> 1;                 // 0: hi plane (k<16), 1: lo plane (k>=16)

  // ---- stage W[o, ic*64..+64) transposed: Wt[li][e][d], e-stride 20 ----
  // stride-20 pad => ds_read_b128 across e is bank-conflict-free
  {
    const float4* Wg = (const float4*)(W + ((size_t)o * 1152 + (size_t)ic * 64) * 128);
    for (int l = t; l < 2048; l += 256) {
      float4 w = Wg[l];
      int li = l >> 5;              // 32 float4 per li
      int rem = l & 31;
      int d = rem >> 1;             // 2 float4 per d (8 e's)
      int e0 = (rem & 1) << 2;
      float* dst = &Wt[li * 160 + e0 * 20 + d];
      dst[0] = w.x; dst[20] = w.y; dst[40] = w.z; dst[60] = w.w;
    }
  }

  // ---- B fragments (v), once per lane: B1 = vh everywhere; B2 = vl / 0 ----
  bf8_t B1[8], B2[8];
  #pragma unroll
  for (int nt = 0; nt < 8; ++nt) {
    int b = nt * 16 + lr;
    float vv[8];
    #pragma unroll
    for (int j = 0; j < 8; ++j)
      vv[j] = vt[((size_t)o * 16 + dhalf + j) * 128 + b];
    unsigned h[4], l2[4];
    cvt_hilo8(vv, h, l2);
    uint4 uh = make_uint4(h[0], h[1], h[2], h[3]);
    uint4 ul = (lq < 2) ? make_uint4(l2[0], l2[1], l2[2], l2[3])
                        : make_uint4(0u, 0u, 0u, 0u);
    B1[nt] = *(const bf8_t*)&uh;
    B2[nt] = *(const bf8_t*)&ul;
  }
  __syncthreads();

  unsigned lomask = hl ? 0xFFFF0000u : 0u;   // hi lanes pack f; lo lanes pack f-trunc(f)

  // wave owns 8 M-tiles (16 li); loops all 8 b-tiles
  for (int mi = 0; mi < 8; ++mi) {
    int mt = wave * 8 + mi;
    // A fragment: row = lr -> (li = mt*2 + lr>>3, e = lr&7); elem j -> d = dhalf+j
    int liA = mt * 2 + (lr >> 3);
    int eA = lr & 7;
    const float* wp = &Wt[liA * 160 + eA * 20 + dhalf];
    float4 wa = *(const float4*)wp;
    float4 wb = *(const float4*)(wp + 4);
    float fw[8] = {wa.x, wa.y, wa.z, wa.w, wb.x, wb.y, wb.z, wb.w};
    unsigned ha[4];
    #pragma unroll
    for (int j = 0; j < 4; ++j) {
      float f0 = fw[2 * j], f1 = fw[2 * j + 1];
      f0 -= __uint_as_float(__float_as_uint(f0) & lomask);
      f1 -= __uint_as_float(__float_as_uint(f1) & lomask);
      ha[j] = (__float_as_uint(f0) >> 16) | (__float_as_uint(f1) & 0xFFFF0000u);
    }
    uint4 ua = make_uint4(ha[0], ha[1], ha[2], ha[3]);
    bf8_t A = *(const bf8_t*)&ua;

    // D rows this lane holds: row = lq*4 + r -> li = mt*2 + (lq>>1), e = (lq&1)*4 + r
    int gi = ic * 64 + mt * 2 + hl;
    const float* up = ut + (size_t)gi * 1024 + (size_t)(((lq & 1) << 2)) * 128;
    #pragma unroll
    for (int nt = 0; nt < 8; ++nt) {
      f4_t acc = (f4_t)0.0f;
      acc = __builtin_amdgcn_mfma_f32_16x16x32_bf16(A, B1[nt], acc, 0, 0, 0);
      acc = __builtin_amdgcn_mfma_f32_16x16x32_bf16(A, B2[nt], acc, 0, 0, 0);
      int b = nt * 16 + lr;
      float p = acc[0] * up[b] + acc[1] * up[128 + b] +
                acc[2] * up[256 + b] + acc[3] * up[384 + b];
      p += __shfl_xor(p, 16);     // combine complementary e-halves (lq ^ 1)
      if (!(lq & 1)) {            // lq=0 writes li even, lq=2 writes li odd
        size_t off = ((size_t)o * 1152 + gi) * 128 + b;
        if (accum) blogt[off] += p; else blogt[off] = p;
      }
    }
  }
}

// ---------- softmax over o per (i,b), transposed layouts ----------
__global__ __launch_bounds__(256) void caps_softmax(
    const float* __restrict__ blogt, float* __restrict__ ct)
{
  int idx = blockIdx.x * 256 + threadIdx.x;
  if (idx >= 147456) return;
  const float* bp = blogt + idx;
  float m = -3.4e38f;
  for (int o = 0; o < 100; ++o) m = fmaxf(m, bp[(size_t)o * 147456]);
  float sum = 0.f;
  for (int o = 0; o < 100; ++o) sum += __expf(bp[(size_t)o * 147456] - m);
  float inv = 1.f / sum;
  for (int o = 0; o < 100; ++o)
    ct[(size_t)o * 147456 + idx] = __expf(bp[(size_t)o * 147456] - m) * inv;
}

// ---------- bias + optional relu, in place ----------
__global__ __launch_bounds__(256) void bias_act_k(
    float* __restrict__ C, const float* __restrict__ bias, int N, int total, int relu)
{
  int idx = blockIdx.x * 256 + threadIdx.x;
  if (idx >= total) return;
  float vv = C[idx] + bias[idx % N];
  if (relu) vv = fmaxf(vv, 0.f);
  C[idx] = vv;
}

// ---------- fc3 ----------
__global__ __launch_bounds__(128) void fc3_seed(
    const float* __restrict__ bias, float* __restrict__ out)
{
  int idx = blockIdx.x * 128 + threadIdx.x;
  if (idx < 12800) out[idx] = bias[idx % 100];
}

__global__ __launch_bounds__(128) void fc3_sk(
    const float* __restrict__ A, const float* __restrict__ W,
    float* __restrict__ out)
{
  __shared__ float Al[1024];
  int m = blockIdx.x, z = blockIdx.y, t = threadIdx.x;
  int kbeg = z * 1024;
  const float* ap = A + (size_t)m * 4096 + kbeg;
  for (int l = t; l < 1024; l += 128) Al[l] = ap[l];
  __syncthreads();
  if (t < 100) {
    float acc = 0.f;
    const float* wp = W + (size_t)kbeg * 100 + t;
    #pragma unroll 8
    for (int k = 0; k < 1024; ++k) acc += Al[k] * wp[(size_t)k * 100];
    atomicAdd(out + m * 100 + t, acc);
  }
}

// ============================================================================
extern "C" void kernel_launch(void* const* d_in, const int* in_sizes, int n_in,
                              void* d_out, int out_size, void* d_ws, size_t ws_size,
                              hipStream_t stream)
{
  (void)in_sizes; (void)n_in; (void)out_size; (void)ws_size;
  const float* x   = (const float*)d_in[0];
  const float* cw1 = (const float*)d_in[1];
  const float* cb1 = (const float*)d_in[2];
  const float* cw2 = (const float*)d_in[3];
  const float* cb2 = (const float*)d_in[4];
  const float* cw3 = (const float*)d_in[5];
  const float* cb3 = (const float*)d_in[6];
  const float* pw  = (const float*)d_in[7];
  const float* pb  = (const float*)d_in[8];
  const float* Wc  = (const float*)d_in[9];
  const float* fw1 = (const float*)d_in[10];
  const float* fb1 = (const float*)d_in[11];
  const float* fw2 = (const float*)d_in[12];
  const float* fb2 = (const float*)d_in[13];
  const float* fw3 = (const float*)d_in[14];
  const float* fb3 = (const float*)d_in[15];
  float* ws = (float*)d_ws;

  const size_t OFF_A  = 0;          // h1/h2/h3 ; later blog_t [o,i,b]
  const size_t OFF_B  = 12582912;   // h1p / h2p
  const size_t OFF_U  = 15728640;   // u_t [1152,8,128]
  const size_t OFF_P  = 16908288;   // p [128,256,36]; later v_t [100,16,128]
  const size_t OFF_C  = 18087936;   // c_t [100,1152,128]
  const size_t OFF_V  = 32833536;   // v [128,100,16]
  const size_t OFF_S  = 33038336;   // s [128,100,16]
  const size_t OFF_F1 = 33243136;   // f1 [128,4096]
  const size_t OFF_F2 = 33767424;   // f2 [128,4096]

  float* A     = ws + OFF_A;
  float* Bf    = ws + OFF_B;
  float* ut    = ws + OFF_U;
  float* p     = ws + OFF_P;
  float* vt    = ws + OFF_P;        // reuses p region after squash8
  float* ct    = ws + OFF_C;
  float* v     = ws + OFF_V;
  float* s     = ws + OFF_S;
  float* f1    = ws + OFF_F1;
  float* f2    = ws + OFF_F2;
  float* blogt = ws + OFF_A;

  hipMemsetAsync(p,  0, (size_t)1179648 * 4, stream);
  hipMemsetAsync(f1, 0, (size_t)524288 * 4, stream);
  hipMemsetAsync(f2, 0, (size_t)524288 * 4, stream);

  // Backbone
  conv1_k<<<49152, 256, 0, stream>>>(x, cw1, cb1, A);                 // [128,96,32,32]
  maxpool_k<<<12288, 256, 0, stream>>>(A, Bf, 32);                    // [128,96,16,16]
  convgemm_mfma<96, 16, 1, 16, false><<<dim3(512, 4), 256, 0, stream>>>(Bf, cw2, cb2, A, 256, 1, 0);
  maxpool_k<<<8192, 256, 0, stream>>>(A, Bf, 16);                     // [128,256,8,8]
  convgemm_mfma<256, 8, 1, 8, false><<<dim3(128, 6), 256, 0, stream>>>(Bf, cw3, cb3, A, 384, 1, 0);
  convgemm_mfma<384, 8, 0, 6, true><<<dim3(72, 4, 2), 256, 0, stream>>>(A, pw, pb, p, 256, 0, 1728);
  squash8_k<<<576, 256, 0, stream>>>(p, pb, ut);                      // u_t [1152,8,128]

  // Dynamic routing (3 iterations), x_hat recomputed on the fly via MFMA.
  // blogt memset no longer needed: r=0 b-update stores (accum=0).
  for (int r = 0; r < 3; ++r) {
    hipMemsetAsync(s, 0, (size_t)204800 * 4, stream);
    if (r == 0) {
      caps_spass_mfma<<<dim3(100, 8), 256, 0, stream>>>(Wc, ut, ut /*dummy*/, s, 1);
    } else {
      caps_softmax<<<576, 256, 0, stream>>>(blogt, ct);
      caps_spass_mfma<<<dim3(100, 8), 256, 0, stream>>>(Wc, ut, ct, s, 0);
    }
    caps_squash16<<<50, 256, 0, stream>>>(s, v, vt);
    if (r < 2)
      caps_bupdate<<<dim3(100, 18), 256, 0, stream>>>(Wc, ut, vt, blogt, r);
  }

  // FC head; v is already [128,1600] flat
  fc_mfma<<<dim3(64, 2, 2), 256, 0, stream>>>(v,  fw1, f1, 1600, 4096, 800);
  bias_act_k<<<2048, 256, 0, stream>>>(f1, fb1, 4096, 524288, 1);
  fc_mfma<<<dim3(64, 2, 4), 256, 0, stream>>>(f1, fw2, f2, 4096, 4096, 1024);
  bias_act_k<<<2048, 256, 0, stream>>>(f2, fb2, 4096, 524288, 1);
  fc3_seed<<<100, 128, 0, stream>>>(fb3, (float*)d_out);
  fc3_sk<<<dim3(128, 4), 128, 0, stream>>>(f2, fw3, (float*)d_out);
}

// Round 2
// 1045.335 us; speedup vs baseline: 1.3114x; 1.0976x over previous
//
#include <hip/hip_runtime.h>
#include <cstddef>

// ============================================================================
// AlexCapsNet CIFAR-100 forward. Round 8: conv1 rewritten with register-window
// reuse. Each thread holds its 3x3x3 input window (27 VGPRs) and sweeps a
// 24-channel co-slice with wave-uniform weight reads (scalar cache / SGPR
// operands), 648 FMA per thread instead of 27 -> load latency amortized 24x.
// Everything else unchanged from round 7.
// ============================================================================

typedef __attribute__((ext_vector_type(8))) short bf8_t;   // 8 bf16 (4 VGPR)
typedef __attribute__((ext_vector_type(4))) float f4_t;    // 4 fp32 acc

// pack 8 fp32 -> 4 dwords of bf16-hi pairs + 4 dwords of bf16-lo pairs
__device__ inline void cvt_hilo8(const float* f, unsigned* h, unsigned* l)
{
  #pragma unroll
  for (int j = 0; j < 4; ++j) {
    unsigned u0 = __float_as_uint(f[2 * j]);
    unsigned u1 = __float_as_uint(f[2 * j + 1]);
    h[j] = (u0 >> 16) | (u1 & 0xFFFF0000u);
    float r0 = f[2 * j]     - __uint_as_float(u0 & 0xFFFF0000u);
    float r1 = f[2 * j + 1] - __uint_as_float(u1 & 0xFFFF0000u);
    l[j] = (__float_as_uint(r0) >> 16) | (__float_as_uint(r1) & 0xFFFF0000u);
  }
}

// ---------- conv1: 3->96 k3 s1 p1 + relu, register-window + co-slice ----------
__global__ __launch_bounds__(256) void conv1_k(
    const float* __restrict__ x, const float* __restrict__ wt,
    const float* __restrict__ bias, float* __restrict__ out)
{
  int idx = blockIdx.x * 256 + threadIdx.x;     // (b, h, w)
  int w = idx & 31, h = (idx >> 5) & 31, b = idx >> 10;
  int co0 = blockIdx.y * 24;                    // co-slice

  float xv[27];
  const float* xb = x + (size_t)b * 3072;
  #pragma unroll
  for (int ci = 0; ci < 3; ++ci)
    #pragma unroll
    for (int dh = 0; dh < 3; ++dh) {
      int ih = h + dh - 1;
      #pragma unroll
      for (int dw = 0; dw < 3; ++dw) {
        int iw = w + dw - 1;
        bool ok = ((unsigned)ih < 32u) & ((unsigned)iw < 32u);
        xv[ci * 9 + dh * 3 + dw] = ok ? xb[(ci << 10) + (ih << 5) + iw] : 0.f;
      }
    }

  float* op = out + (size_t)b * 98304 + ((size_t)co0 << 10) + (h << 5) + w;
  const float* wp = wt + (size_t)co0 * 27;      // wave-uniform -> s_load
  #pragma unroll 2
  for (int co = 0; co < 24; ++co) {
    float acc = bias[co0 + co];
    #pragma unroll
    for (int k = 0; k < 27; ++k)
      acc += xv[k] * wp[co * 27 + k];
    op[(size_t)co << 10] = fmaxf(acc, 0.f);
  }
}

// ---------- maxpool k3 s2 p1 ----------
__global__ __launch_bounds__(256) void maxpool_k(
    const float* __restrict__ in, float* __restrict__ out, int H)
{
  int Ho = H >> 1;
  int idx = blockIdx.x * 256 + threadIdx.x;
  int wo = idx % Ho;
  int t2 = idx / Ho;
  int ho = t2 % Ho;
  int bc = t2 / Ho;
  const float* ip = in + (size_t)bc * H * H;
  float m = -3.4e38f;
  #pragma unroll
  for (int dh = 0; dh < 3; ++dh) {
    int ih = 2 * ho - 1 + dh;
    if (ih < 0 || ih >= H) continue;
    #pragma unroll
    for (int dw = 0; dw < 3; ++dw) {
      int iw = 2 * wo - 1 + dw;
      if (iw < 0 || iw >= H) continue;
      m = fmaxf(m, ip[ih * H + iw]);
    }
  }
  out[idx] = m;
}

// ---------- conv as bf16x2-split MFMA GEMM with on-the-fly im2col ----------
template <int CI, int H, int PAD, int WO, bool SPLIT>
__global__ __launch_bounds__(256) void convgemm_mfma(
    const float* __restrict__ in, const float* __restrict__ wt,
    const float* __restrict__ bias, float* __restrict__ out,
    int CO, int relu, int KC)
{
  constexpr int K = CI * 9;
  constexpr int NPIX = WO * WO;
  __shared__ uint4 Ah[256], Al[256], Bh[256], Bl[256];
  int n0 = blockIdx.x * 64, m0 = blockIdx.y * 64;
  int kbeg = SPLIT ? blockIdx.z * KC : 0;
  int kend = SPLIT ? kbeg + KC : K;
  int t = threadIdx.x;
  int lane = t & 63;
  int wave = __builtin_amdgcn_readfirstlane(t >> 6);
  int wm = wave & 1, wn = wave >> 1;
  int lr = lane & 15, lq = lane >> 4;
  int smA = t >> 2, sgA = t & 3;

  int nn = n0 + lane;
  int bb = nn / NPIX, xy = nn - bb * NPIX;
  int ho = xy / WO, wo = xy - ho * WO;
  int ih0 = ho - PAD, iw0 = wo - PAD;
  const float* inb = in + (size_t)bb * CI * H * H;

  float fa[8], fb[8];
  auto loadA = [&](int k0) {
    const float4* ap = (const float4*)(wt + (size_t)(m0 + smA) * K + k0 + sgA * 8);
    float4 a0 = ap[0], a1 = ap[1];
    fa[0] = a0.x; fa[1] = a0.y; fa[2] = a0.z; fa[3] = a0.w;
    fa[4] = a1.x; fa[5] = a1.y; fa[6] = a1.z; fa[7] = a1.w;
  };
  auto loadB = [&](int k0) {
    int kb = k0 + wave * 8;
    int ci = kb / 9, rr = kb - ci * 9;
    int dh = rr / 3, dw = rr - dh * 3;
    #pragma unroll
    for (int j = 0; j < 8; ++j) {
      int ih = ih0 + dh, iw = iw0 + dw;
      bool ok = (ih >= 0 && ih < H && iw >= 0 && iw < H);
      fb[j] = ok ? inb[(ci * H + ih) * H + iw] : 0.f;
      if (++dw == 3) { dw = 0; if (++dh == 3) { dh = 0; ++ci; } }
    }
  };

  loadA(kbeg); loadB(kbeg);
  f4_t acc[2][2];
  #pragma unroll
  for (int mt = 0; mt < 2; ++mt)
    #pragma unroll
    for (int nt = 0; nt < 2; ++nt) acc[mt][nt] = (f4_t)0.0f;

  for (int k0 = kbeg; k0 < kend; k0 += 32) {
    if (k0 > kbeg) __syncthreads();
    unsigned ha[4], la[4], hb[4], lb[4];
    cvt_hilo8(fa, ha, la);
    cvt_hilo8(fb, hb, lb);
    Ah[sgA * 64 + smA] = make_uint4(ha[0], ha[1], ha[2], ha[3]);
    Al[sgA * 64 + smA] = make_uint4(la[0], la[1], la[2], la[3]);
    Bh[wave * 64 + lane] = make_uint4(hb[0], hb[1], hb[2], hb[3]);
    Bl[wave * 64 + lane] = make_uint4(lb[0], lb[1], lb[2], lb[3]);
    __syncthreads();
    if (k0 + 32 < kend) { loadA(k0 + 32); loadB(k0 + 32); }
    bf8_t av_h[2], av_l[2], bv_h[2], bv_l[2];
    #pragma unroll
    for (int mt = 0; mt < 2; ++mt) {
      int ui = lq * 64 + wm * 32 + mt * 16 + lr;
      av_h[mt] = *(const bf8_t*)&Ah[ui];
      av_l[mt] = *(const bf8_t*)&Al[ui];
    }
    #pragma unroll
    for (int nt = 0; nt < 2; ++nt) {
      int ui = lq * 64 + wn * 32 + nt * 16 + lr;
      bv_h[nt] = *(const bf8_t*)&Bh[ui];
      bv_l[nt] = *(const bf8_t*)&Bl[ui];
    }
    #pragma unroll
    for (int mt = 0; mt < 2; ++mt)
      #pragma unroll
      for (int nt = 0; nt < 2; ++nt) {
        acc[mt][nt] = __builtin_amdgcn_mfma_f32_16x16x32_bf16(av_h[mt], bv_h[nt], acc[mt][nt], 0, 0, 0);
        acc[mt][nt] = __builtin_amdgcn_mfma_f32_16x16x32_bf16(av_h[mt], bv_l[nt], acc[mt][nt], 0, 0, 0);
        acc[mt][nt] = __builtin_amdgcn_mfma_f32_16x16x32_bf16(av_l[mt], bv_h[nt], acc[mt][nt], 0, 0, 0);
      }
  }
  #pragma unroll
  for (int mt = 0; mt < 2; ++mt)
    #pragma unroll
    for (int nt = 0; nt < 2; ++nt) {
      #pragma unroll
      for (int r = 0; r < 4; ++r) {
        int m = m0 + wm * 32 + mt * 16 + lq * 4 + r;
        int n = n0 + wn * 32 + nt * 16 + lr;
        int b = n / NPIX, pxy = n - b * NPIX;
        size_t oidx = ((size_t)b * CO + m) * NPIX + pxy;
        if (SPLIT) {
          atomicAdd(out + oidx, acc[mt][nt][r]);
        } else {
          float vv = acc[mt][nt][r] + bias[m];
          if (relu) vv = fmaxf(vv, 0.f);
          out[oidx] = vv;
        }
      }
    }
}

// ---------- FC as bf16x2-split MFMA GEMM, split-K, atomic partials ----------
__global__ __launch_bounds__(256) void fc_mfma(
    const float* __restrict__ A, const float* __restrict__ W,
    float* __restrict__ C, int K, int N, int KC)
{
  __shared__ uint4 Ah[256], Al[256], Bh[256], Bl[256];
  int n0 = blockIdx.x * 64, m0 = blockIdx.y * 64;
  int kbeg = blockIdx.z * KC, kend = kbeg + KC;
  int t = threadIdx.x;
  int lane = t & 63;
  int wave = __builtin_amdgcn_readfirstlane(t >> 6);
  int wm = wave & 1, wn = wave >> 1;
  int lr = lane & 15, lq = lane >> 4;
  int smA = t >> 2, sgA = t & 3;

  float fa[8], fb[8];
  auto loadA = [&](int k0) {
    const float4* ap = (const float4*)(A + (size_t)(m0 + smA) * K + k0 + sgA * 8);
    float4 a0 = ap[0], a1 = ap[1];
    fa[0] = a0.x; fa[1] = a0.y; fa[2] = a0.z; fa[3] = a0.w;
    fa[4] = a1.x; fa[5] = a1.y; fa[6] = a1.z; fa[7] = a1.w;
  };
  auto loadB = [&](int k0) {
    const float* wp = W + (size_t)(k0 + wave * 8) * N + n0 + lane;
    #pragma unroll
    for (int j = 0; j < 8; ++j) fb[j] = wp[(size_t)j * N];
  };

  loadA(kbeg); loadB(kbeg);
  f4_t acc[2][2];
  #pragma unroll
  for (int mt = 0; mt < 2; ++mt)
    #pragma unroll
    for (int nt = 0; nt < 2; ++nt) acc[mt][nt] = (f4_t)0.0f;

  for (int k0 = kbeg; k0 < kend; k0 += 32) {
    if (k0 > kbeg) __syncthreads();
    unsigned ha[4], la[4], hb[4], lb[4];
    cvt_hilo8(fa, ha, la);
    cvt_hilo8(fb, hb, lb);
    Ah[sgA * 64 + smA] = make_uint4(ha[0], ha[1], ha[2], ha[3]);
    Al[sgA * 64 + smA] = make_uint4(la[0], la[1], la[2], la[3]);
    Bh[wave * 64 + lane] = make_uint4(hb[0], hb[1], hb[2], hb[3]);
    Bl[wave * 64 + lane] = make_uint4(lb[0], lb[1], lb[2], lb[3]);
    __syncthreads();
    if (k0 + 32 < kend) { loadA(k0 + 32); loadB(k0 + 32); }
    bf8_t av_h[2], av_l[2], bv_h[2], bv_l[2];
    #pragma unroll
    for (int mt = 0; mt < 2; ++mt) {
      int ui = lq * 64 + wm * 32 + mt * 16 + lr;
      av_h[mt] = *(const bf8_t*)&Ah[ui];
      av_l[mt] = *(const bf8_t*)&Al[ui];
    }
    #pragma unroll
    for (int nt = 0; nt < 2; ++nt) {
      int ui = lq * 64 + wn * 32 + nt * 16 + lr;
      bv_h[nt] = *(const bf8_t*)&Bh[ui];
      bv_l[nt] = *(const bf8_t*)&Bl[ui];
    }
    #pragma unroll
    for (int mt = 0; mt < 2; ++mt)
      #pragma unroll
      for (int nt = 0; nt < 2; ++nt) {
        acc[mt][nt] = __builtin_amdgcn_mfma_f32_16x16x32_bf16(av_h[mt], bv_h[nt], acc[mt][nt], 0, 0, 0);
        acc[mt][nt] = __builtin_amdgcn_mfma_f32_16x16x32_bf16(av_h[mt], bv_l[nt], acc[mt][nt], 0, 0, 0);
        acc[mt][nt] = __builtin_amdgcn_mfma_f32_16x16x32_bf16(av_l[mt], bv_h[nt], acc[mt][nt], 0, 0, 0);
      }
  }
  #pragma unroll
  for (int mt = 0; mt < 2; ++mt)
    #pragma unroll
    for (int nt = 0; nt < 2; ++nt) {
      #pragma unroll
      for (int r = 0; r < 4; ++r) {
        int m = m0 + wm * 32 + mt * 16 + lq * 4 + r;
        int n = n0 + wn * 32 + nt * 16 + lr;
        atomicAdd(C + (size_t)m * N + n, acc[mt][nt][r]);
      }
    }
}

// ---------- squash8 + pcaps bias; p[b,256,36] partials -> u_t[i,e,b] ----------
__global__ __launch_bounds__(256) void squash8_k(
    const float* __restrict__ p, const float* __restrict__ pb,
    float* __restrict__ ut)
{
  int idx = blockIdx.x * 256 + threadIdx.x;
  if (idx >= 147456) return;
  int b = idx & 127, i = idx >> 7;
  const float4* pp = (const float4*)(p + ((size_t)b * 1152 + i) * 8);
  float4 a = pp[0], bb = pp[1];
  float pv[8] = {a.x, a.y, a.z, a.w, bb.x, bb.y, bb.z, bb.w};
  int f0 = i * 8;
  #pragma unroll
  for (int e = 0; e < 8; ++e) pv[e] += pb[(f0 + e) / 36];
  float n2 = 0.f;
  #pragma unroll
  for (int e = 0; e < 8; ++e) n2 += pv[e] * pv[e];
  float sc = (n2 / (1.f + n2)) * rsqrtf(n2 + 1e-8f);
  #pragma unroll
  for (int e = 0; e < 8; ++e)
    ut[(size_t)i * 1024 + e * 128 + b] = pv[e] * sc;
}

// ---------- squash16: s[b,o,16] -> v[b,o,16] + v_t[o,d,b] ----------
__global__ __launch_bounds__(256) void caps_squash16(
    const float* __restrict__ s, float* __restrict__ v, float* __restrict__ vt)
{
  int idx = blockIdx.x * 256 + threadIdx.x;
  if (idx >= 12800) return;
  int b = idx / 100, o = idx % 100;
  const float4* sp = (const float4*)(s + (size_t)idx * 16);
  float4 a = sp[0], bb = sp[1], c = sp[2], d = sp[3];
  float n2 = a.x * a.x + a.y * a.y + a.z * a.z + a.w * a.w +
             bb.x * bb.x + bb.y * bb.y + bb.z * bb.z + bb.w * bb.w +
             c.x * c.x + c.y * c.y + c.z * c.z + c.w * c.w +
             d.x * d.x + d.y * d.y + d.z * d.z + d.w * d.w;
  float sc = (n2 / (1.f + n2)) * rsqrtf(n2 + 1e-8f);
  float vv[16] = {a.x, a.y, a.z, a.w, bb.x, bb.y, bb.z, bb.w,
                  c.x, c.y, c.z, c.w, d.x, d.y, d.z, d.w};
  float4* vp = (float4*)(v + (size_t)idx * 16);
  float4 o0 = {vv[0] * sc, vv[1] * sc, vv[2] * sc, vv[3] * sc};
  float4 o1 = {vv[4] * sc, vv[5] * sc, vv[6] * sc, vv[7] * sc};
  float4 o2 = {vv[8] * sc, vv[9] * sc, vv[10] * sc, vv[11] * sc};
  float4 o3 = {vv[12] * sc, vv[13] * sc, vv[14] * sc, vv[15] * sc};
  vp[0] = o0; vp[1] = o1; vp[2] = o2; vp[3] = o3;
  #pragma unroll
  for (int dd = 0; dd < 16; ++dd)
    vt[((size_t)o * 16 + dd) * 128 + b] = vv[dd] * sc;
}

// ---------- routing s-pass as per-o MFMA GEMM ----------
__global__ __launch_bounds__(256) void caps_spass_mfma(
    const float* __restrict__ W, const float* __restrict__ ut,
    const float* __restrict__ ct, float* __restrict__ s, int uniform)
{
  __shared__ uint4 Ah[512], Al[512];               // [quad(4)][b(128)] 8KB each
  int o = blockIdx.x, ks = blockIdx.y;
  int t = threadIdx.x;
  int lane = t & 63;
  int wave = __builtin_amdgcn_readfirstlane(t >> 6);
  int lr = lane & 15, lq = lane >> 4;
  int b = t & 127, half = t >> 7;                  // staging role
  int i0 = ks * 144;

  float fu[16], fc[2], fw[8];
  auto loadUC = [&](int j) {
    int ib = i0 + j * 4 + half * 2;
    #pragma unroll
    for (int q = 0; q < 2; ++q) {
      int i = ib + q;
      #pragma unroll
      for (int e = 0; e < 8; ++e)
        fu[q * 8 + e] = ut[(size_t)i * 1024 + e * 128 + b];   // coalesced
      fc[q] = uniform ? 0.01f : ct[((size_t)o * 1152 + i) * 128 + b];
    }
  };
  auto loadW = [&](int j) {
    int i = i0 + j * 4 + lq;
    const float4* wp = (const float4*)(W + (((size_t)o * 1152 + i) * 16 + lr) * 8);
    float4 w0 = wp[0], w1 = wp[1];
    fw[0] = w0.x; fw[1] = w0.y; fw[2] = w0.z; fw[3] = w0.w;
    fw[4] = w1.x; fw[5] = w1.y; fw[6] = w1.z; fw[7] = w1.w;
  };

  loadUC(0); loadW(0);
  f4_t acc[2];
  acc[0] = (f4_t)0.0f; acc[1] = (f4_t)0.0f;

  for (int j = 0; j < 36; ++j) {
    float cu[16];
    #pragma unroll
    for (int q = 0; q < 2; ++q)
      #pragma unroll
      for (int e = 0; e < 8; ++e)
        cu[q * 8 + e] = fc[q] * fu[q * 8 + e];
    unsigned h0[4], l0[4], h1[4], l1[4], wh[4], wl[4];
    cvt_hilo8(cu, h0, l0);
    cvt_hilo8(cu + 8, h1, l1);
    cvt_hilo8(fw, wh, wl);                          // current W split (before prefetch)
    uint4 uwh = make_uint4(wh[0], wh[1], wh[2], wh[3]);
    uint4 uwl = make_uint4(wl[0], wl[1], wl[2], wl[3]);
    bf8_t bfh = *(const bf8_t*)&uwh;
    bf8_t bfl = *(const bf8_t*)&uwl;
    if (j > 0) __syncthreads();
    Ah[(half * 2 + 0) * 128 + b] = make_uint4(h0[0], h0[1], h0[2], h0[3]);
    Al[(half * 2 + 0) * 128 + b] = make_uint4(l0[0], l0[1], l0[2], l0[3]);
    Ah[(half * 2 + 1) * 128 + b] = make_uint4(h1[0], h1[1], h1[2], h1[3]);
    Al[(half * 2 + 1) * 128 + b] = make_uint4(l1[0], l1[1], l1[2], l1[3]);
    __syncthreads();
    if (j + 1 < 36) { loadUC(j + 1); loadW(j + 1); }
    #pragma unroll
    for (int mt = 0; mt < 2; ++mt) {
      int bidx = wave * 16 + mt * 64 + lr;
      bf8_t avh = *(const bf8_t*)&Ah[lq * 128 + bidx];
      bf8_t avl = *(const bf8_t*)&Al[lq * 128 + bidx];
      acc[mt] = __builtin_amdgcn_mfma_f32_16x16x32_bf16(avh, bfh, acc[mt], 0, 0, 0);
      acc[mt] = __builtin_amdgcn_mfma_f32_16x16x32_bf16(avh, bfl, acc[mt], 0, 0, 0);
      acc[mt] = __builtin_amdgcn_mfma_f32_16x16x32_bf16(avl, bfh, acc[mt], 0, 0, 0);
    }
  }
  // D layout: col(d)=lane&15, row(b)=lq*4+r
  #pragma unroll
  for (int mt = 0; mt < 2; ++mt)
    #pragma unroll
    for (int r = 0; r < 4; ++r) {
      int bb = wave * 16 + mt * 64 + lq * 4 + r;
      atomicAdd(s + ((size_t)bb * 100 + o) * 16 + lr, acc[mt][r]);
    }
}

// ---------- routing b-update as MFMA ----------
// blog[o,i,b] (+)= sum_e u[b,i,e] * T[i,e,b],  T = sum_d W[o,i,d,e] v[b,o,d]
__global__ __launch_bounds__(256) void caps_bupdate(
    const float* __restrict__ W, const float* __restrict__ ut,
    const float* __restrict__ vt, float* __restrict__ blogt, int accum)
{
  __shared__ __align__(16) float Wt[64 * 160];   // [li][e(stride 20)][d] 40KB
  int o = blockIdx.x, ic = blockIdx.y;
  int t = threadIdx.x;
  int lane = t & 63;
  int wave = __builtin_amdgcn_readfirstlane(t >> 6);
  int lr = lane & 15, lq = lane >> 4;
  int dhalf = (lq & 1) << 3;        // which 8 d's this lq-quarter covers
  int hl = lq >> 1;                 // 0: hi plane (k<16), 1: lo plane (k>=16)

  // ---- stage W[o, ic*64..+64) transposed: Wt[li][e][d], e-stride 20 ----
  {
    const float4* Wg = (const float4*)(W + ((size_t)o * 1152 + (size_t)ic * 64) * 128);
    for (int l = t; l < 2048; l += 256) {
      float4 w = Wg[l];
      int li = l >> 5;              // 32 float4 per li
      int rem = l & 31;
      int d = rem >> 1;             // 2 float4 per d (8 e's)
      int e0 = (rem & 1) << 2;
      float* dst = &Wt[li * 160 + e0 * 20 + d];
      dst[0] = w.x; dst[20] = w.y; dst[40] = w.z; dst[60] = w.w;
    }
  }

  // ---- B fragments (v), once per lane: B1 = vh everywhere; B2 = vl / 0 ----
  bf8_t B1[8], B2[8];
  #pragma unroll
  for (int nt = 0; nt < 8; ++nt) {
    int b = nt * 16 + lr;
    float vv[8];
    #pragma unroll
    for (int j = 0; j < 8; ++j)
      vv[j] = vt[((size_t)o * 16 + dhalf + j) * 128 + b];
    unsigned h[4], l2[4];
    cvt_hilo8(vv, h, l2);
    uint4 uh = make_uint4(h[0], h[1], h[2], h[3]);
    uint4 ul = (lq < 2) ? make_uint4(l2[0], l2[1], l2[2], l2[3])
                        : make_uint4(0u, 0u, 0u, 0u);
    B1[nt] = *(const bf8_t*)&uh;
    B2[nt] = *(const bf8_t*)&ul;
  }
  __syncthreads();

  unsigned lomask = hl ? 0xFFFF0000u : 0u;   // hi lanes pack f; lo lanes pack f-trunc(f)

  // wave owns 8 M-tiles (16 li); loops all 8 b-tiles
  for (int mi = 0; mi < 8; ++mi) {
    int mt = wave * 8 + mi;
    int liA = mt * 2 + (lr >> 3);
    int eA = lr & 7;
    const float* wp = &Wt[liA * 160 + eA * 20 + dhalf];
    float4 wa = *(const float4*)wp;
    float4 wb = *(const float4*)(wp + 4);
    float fw[8] = {wa.x, wa.y, wa.z, wa.w, wb.x, wb.y, wb.z, wb.w};
    unsigned ha[4];
    #pragma unroll
    for (int j = 0; j < 4; ++j) {
      float f0 = fw[2 * j], f1 = fw[2 * j + 1];
      f0 -= __uint_as_float(__float_as_uint(f0) & lomask);
      f1 -= __uint_as_float(__float_as_uint(f1) & lomask);
      ha[j] = (__float_as_uint(f0) >> 16) | (__float_as_uint(f1) & 0xFFFF0000u);
    }
    uint4 ua = make_uint4(ha[0], ha[1], ha[2], ha[3]);
    bf8_t A = *(const bf8_t*)&ua;

    int gi = ic * 64 + mt * 2 + hl;
    const float* up = ut + (size_t)gi * 1024 + (size_t)(((lq & 1) << 2)) * 128;
    #pragma unroll
    for (int nt = 0; nt < 8; ++nt) {
      f4_t acc = (f4_t)0.0f;
      acc = __builtin_amdgcn_mfma_f32_16x16x32_bf16(A, B1[nt], acc, 0, 0, 0);
      acc = __builtin_amdgcn_mfma_f32_16x16x32_bf16(A, B2[nt], acc, 0, 0, 0);
      int b = nt * 16 + lr;
      float p = acc[0] * up[b] + acc[1] * up[128 + b] +
                acc[2] * up[256 + b] + acc[3] * up[384 + b];
      p += __shfl_xor(p, 16);     // combine complementary e-halves (lq ^ 1)
      if (!(lq & 1)) {            // lq=0 writes li even, lq=2 writes li odd
        size_t off = ((size_t)o * 1152 + gi) * 128 + b;
        if (accum) blogt[off] += p; else blogt[off] = p;
      }
    }
  }
}

// ---------- softmax over o per (i,b), transposed layouts ----------
__global__ __launch_bounds__(256) void caps_softmax(
    const float* __restrict__ blogt, float* __restrict__ ct)
{
  int idx = blockIdx.x * 256 + threadIdx.x;
  if (idx >= 147456) return;
  const float* bp = blogt + idx;
  float m = -3.4e38f;
  for (int o = 0; o < 100; ++o) m = fmaxf(m, bp[(size_t)o * 147456]);
  float sum = 0.f;
  for (int o = 0; o < 100; ++o) sum += __expf(bp[(size_t)o * 147456] - m);
  float inv = 1.f / sum;
  for (int o = 0; o < 100; ++o)
    ct[(size_t)o * 147456 + idx] = __expf(bp[(size_t)o * 147456] - m) * inv;
}

// ---------- bias + optional relu, in place ----------
__global__ __launch_bounds__(256) void bias_act_k(
    float* __restrict__ C, const float* __restrict__ bias, int N, int total, int relu)
{
  int idx = blockIdx.x * 256 + threadIdx.x;
  if (idx >= total) return;
  float vv = C[idx] + bias[idx % N];
  if (relu) vv = fmaxf(vv, 0.f);
  C[idx] = vv;
}

// ---------- fc3 ----------
__global__ __launch_bounds__(128) void fc3_seed(
    const float* __restrict__ bias, float* __restrict__ out)
{
  int idx = blockIdx.x * 128 + threadIdx.x;
  if (idx < 12800) out[idx] = bias[idx % 100];
}

__global__ __launch_bounds__(128) void fc3_sk(
    const float* __restrict__ A, const float* __restrict__ W,
    float* __restrict__ out)
{
  __shared__ float Al[1024];
  int m = blockIdx.x, z = blockIdx.y, t = threadIdx.x;
  int kbeg = z * 1024;
  const float* ap = A + (size_t)m * 4096 + kbeg;
  for (int l = t; l < 1024; l += 128) Al[l] = ap[l];
  __syncthreads();
  if (t < 100) {
    float acc = 0.f;
    const float* wp = W + (size_t)kbeg * 100 + t;
    #pragma unroll 8
    for (int k = 0; k < 1024; ++k) acc += Al[k] * wp[(size_t)k * 100];
    atomicAdd(out + m * 100 + t, acc);
  }
}

// ============================================================================
extern "C" void kernel_launch(void* const* d_in, const int* in_sizes, int n_in,
                              void* d_out, int out_size, void* d_ws, size_t ws_size,
                              hipStream_t stream)
{
  (void)in_sizes; (void)n_in; (void)out_size; (void)ws_size;
  const float* x   = (const float*)d_in[0];
  const float* cw1 = (const float*)d_in[1];
  const float* cb1 = (const float*)d_in[2];
  const float* cw2 = (const float*)d_in[3];
  const float* cb2 = (const float*)d_in[4];
  const float* cw3 = (const float*)d_in[5];
  const float* cb3 = (const float*)d_in[6];
  const float* pw  = (const float*)d_in[7];
  const float* pb  = (const float*)d_in[8];
  const float* Wc  = (const float*)d_in[9];
  const float* fw1 = (const float*)d_in[10];
  const float* fb1 = (const float*)d_in[11];
  const float* fw2 = (const float*)d_in[12];
  const float* fb2 = (const float*)d_in[13];
  const float* fw3 = (const float*)d_in[14];
  const float* fb3 = (const float*)d_in[15];
  float* ws = (float*)d_ws;

  const size_t OFF_A  = 0;          // h1/h2/h3 ; later blog_t [o,i,b]
  const size_t OFF_B  = 12582912;   // h1p / h2p
  const size_t OFF_U  = 15728640;   // u_t [1152,8,128]
  const size_t OFF_P  = 16908288;   // p [128,256,36]; later v_t [100,16,128]
  const size_t OFF_C  = 18087936;   // c_t [100,1152,128]
  const size_t OFF_V  = 32833536;   // v [128,100,16]
  const size_t OFF_S  = 33038336;   // s [128,100,16]
  const size_t OFF_F1 = 33243136;   // f1 [128,4096]
  const size_t OFF_F2 = 33767424;   // f2 [128,4096]

  float* A     = ws + OFF_A;
  float* Bf    = ws + OFF_B;
  float* ut    = ws + OFF_U;
  float* p     = ws + OFF_P;
  float* vt    = ws + OFF_P;        // reuses p region after squash8
  float* ct    = ws + OFF_C;
  float* v     = ws + OFF_V;
  float* s     = ws + OFF_S;
  float* f1    = ws + OFF_F1;
  float* f2    = ws + OFF_F2;
  float* blogt = ws + OFF_A;

  hipMemsetAsync(p,  0, (size_t)1179648 * 4, stream);
  hipMemsetAsync(f1, 0, (size_t)524288 * 4, stream);
  hipMemsetAsync(f2, 0, (size_t)524288 * 4, stream);

  // Backbone
  conv1_k<<<dim3(512, 4), 256, 0, stream>>>(x, cw1, cb1, A);          // [128,96,32,32]
  maxpool_k<<<12288, 256, 0, stream>>>(A, Bf, 32);                    // [128,96,16,16]
  convgemm_mfma<96, 16, 1, 16, false><<<dim3(512, 4), 256, 0, stream>>>(Bf, cw2, cb2, A, 256, 1, 0);
  maxpool_k<<<8192, 256, 0, stream>>>(A, Bf, 16);                     // [128,256,8,8]
  convgemm_mfma<256, 8, 1, 8, false><<<dim3(128, 6), 256, 0, stream>>>(Bf, cw3, cb3, A, 384, 1, 0);
  convgemm_mfma<384, 8, 0, 6, true><<<dim3(72, 4, 2), 256, 0, stream>>>(A, pw, pb, p, 256, 0, 1728);
  squash8_k<<<576, 256, 0, stream>>>(p, pb, ut);                      // u_t [1152,8,128]

  // Dynamic routing (3 iterations), x_hat recomputed on the fly via MFMA.
  for (int r = 0; r < 3; ++r) {
    hipMemsetAsync(s, 0, (size_t)204800 * 4, stream);
    if (r == 0) {
      caps_spass_mfma<<<dim3(100, 8), 256, 0, stream>>>(Wc, ut, ut /*dummy*/, s, 1);
    } else {
      caps_softmax<<<576, 256, 0, stream>>>(blogt, ct);
      caps_spass_mfma<<<dim3(100, 8), 256, 0, stream>>>(Wc, ut, ct, s, 0);
    }
    caps_squash16<<<50, 256, 0, stream>>>(s, v, vt);
    if (r < 2)
      caps_bupdate<<<dim3(100, 18), 256, 0, stream>>>(Wc, ut, vt, blogt, r);
  }

  // FC head; v is already [128,1600] flat
  fc_mfma<<<dim3(64, 2, 2), 256, 0, stream>>>(v,  fw1, f1, 1600, 4096, 800);
  bias_act_k<<<2048, 256, 0, stream>>>(f1, fb1, 4096, 524288, 1);
  fc_mfma<<<dim3(64, 2, 4), 256, 0, stream>>>(f1, fw2, f2, 4096, 4096, 1024);
  bias_act_k<<<2048, 256, 0, stream>>>(f2, fb2, 4096, 524288, 1);
  fc3_seed<<<100, 128, 0, stream>>>(fb3, (float*)d_out);
  fc3_sk<<<dim3(128, 4), 128, 0, stream>>>(f2, fw3, (float*)d_out);
}